// Round 16
// baseline (439.122 us; speedup 1.0000x reference)
//
#include <hip/hip_runtime.h>
#include <math.h>

#define BB 2
#define CDIM 256
#define NHEADS 8
#define HD 32
#define HH 40
#define WW 40
#define NN 1600
#define C3 768
#define SCALE 0.17677669529663687f  // 1/sqrt(32)
#define RTE 16           // rows per block, entropy kernel (4 per wave)
#define RTS 2            // rows per block, fallback sparse kernel (1 wave)
#define TSTR 2048        // tile stride: 32 d * 64 jl
#define HSTR 51200       // per (b,part,h): 25 tiles * 2048

typedef __attribute__((ext_vector_type(4))) float f4;

// ---------- helpers ----------
__device__ inline unsigned fkey(float f) {
    unsigned u = __float_as_uint(f);
    return (u & 0x80000000u) ? ~u : (u | 0x80000000u);
}
__device__ inline float finv(unsigned u) {
    unsigned v = (u & 0x80000000u) ? (u ^ 0x80000000u) : ~u;
    return __uint_as_float(v);
}

// ---------- 1x1 conv: 8 output channels per thread ----------
__global__ __launch_bounds__(256) void conv1x1_kernel(const float* __restrict__ x,
                                                      const float* __restrict__ w,
                                                      const float* __restrict__ bias,
                                                      float* __restrict__ out) {
    int blk = blockIdx.x;
    int st = blk % 7;
    int t2 = blk / 7;
    int ocg = t2 % (C3 / 8);
    int b = t2 / (C3 / 8);
    int s = st * 256 + threadIdx.x;
    if (s >= NN) return;
    int oc0 = ocg * 8;
    const float* xb = x + (size_t)b * CDIM * NN + s;
    const float* w0 = w + (size_t)oc0 * CDIM;
    float a[8];
#pragma unroll
    for (int i = 0; i < 8; i++) a[i] = bias[oc0 + i];
#pragma unroll 4
    for (int ic = 0; ic < CDIM; ic++) {
        float xv = xb[(size_t)ic * NN];
#pragma unroll
        for (int i = 0; i < 8; i++) a[i] += w0[i * CDIM + ic] * xv;
    }
    float* ob = out + ((size_t)b * C3 + oc0) * NN + s;
#pragma unroll
    for (int i = 0; i < 8; i++) ob[(size_t)i * NN] = a[i];
}

// ---------- depthwise 3x3 pad1; writes j-tiled layout [b][part][h][kt][d][jl] ----------
__global__ __launch_bounds__(256) void dwconv_kernel(const float* __restrict__ in,
                                                     const float* __restrict__ w,
                                                     const float* __restrict__ bias,
                                                     float* __restrict__ out_t) {
    int idx = blockIdx.x * 256 + threadIdx.x;
    int s = idx % NN;
    int t = idx / NN;
    int c = t % C3;
    int b = t / C3;
    int y = s / WW, xx = s % WW;
    const float* ib = in + ((size_t)b * C3 + c) * NN;
    const float* wr = w + (size_t)c * 9;
    float acc = bias[c];
#pragma unroll
    for (int ky = 0; ky < 3; ky++) {
        int iy = y + ky - 1;
        if (iy < 0 || iy >= HH) continue;
#pragma unroll
        for (int kx = 0; kx < 3; kx++) {
            int ix = xx + kx - 1;
            if (ix < 0 || ix >= WW) continue;
            acc += wr[ky * 3 + kx] * ib[iy * WW + ix];
        }
    }
    int part = c >> 8;
    int r = c & 255;
    int hh = r >> 5;
    int d = r & 31;
    out_t[((size_t)(b * 3 + part) * NHEADS + hh) * HSTR + (s >> 6) * TSTR + d * 64 + (s & 63)] = acc;
}

// ---------- phase 1: streaming entropy, 4 rows per wave; optional attbuf persist ----------
template <int PERSIST>
__global__ __launch_bounds__(256) void entropy_kernel(const float* __restrict__ qkv_t,
                                                      float* __restrict__ ent,
                                                      float* __restrict__ attw) {
    int blk = blockIdx.x;      // bh*(NN/RTE) + rt
    int rt = blk % (NN / RTE);
    int bh = blk / (NN / RTE);
    int h = bh % NHEADS, b = bh / NHEADS;
    int row0 = rt * RTE;
    __shared__ float Qs[RTE][HD];
    int tid = threadIdx.x;
    const float* qt = qkv_t + ((size_t)(b * 3 + 0) * NHEADS + h) * HSTR;
    const float* ktb = qkv_t + ((size_t)(b * 3 + 1) * NHEADS + h) * HSTR;
#pragma unroll
    for (int i = tid; i < RTE * HD; i += 256) {
        int r = i >> 5, d = i & 31;
        int row = row0 + r;
        Qs[r][d] = qt[(row >> 6) * TSTR + d * 64 + (row & 63)];
    }
    __syncthreads();
    int w = tid >> 6, lane = tid & 63;
    int lr0 = 4 * w;                     // this wave's 4 rows
    float* aw0 = nullptr; float* aw1 = nullptr; float* aw2 = nullptr; float* aw3 = nullptr;
    if (PERSIST) {
        aw0 = attw + ((size_t)bh * NN + row0 + lr0) * NN;
        aw1 = aw0 + NN;
        aw2 = aw1 + NN;
        aw3 = aw2 + NN;
    }
    float q0[HD], q1[HD], q2[HD], q3[HD];
#pragma unroll
    for (int d = 0; d < HD; d++) {
        q0[d] = Qs[lr0 + 0][d];
        q1[d] = Qs[lr0 + 1][d];
        q2[d] = Qs[lr0 + 2][d];
        q3[d] = Qs[lr0 + 3][d];
    }
    float S0 = 0.f, T0 = 0.f, S1 = 0.f, T1 = 0.f;
    float S2 = 0.f, T2 = 0.f, S3 = 0.f, T3 = 0.f;
#pragma unroll 1
    for (int kt = 0; kt < 25; kt++) {
        const float* kp = ktb + kt * TSTR + lane;
        float a0 = 0.f, a1 = 0.f, a2 = 0.f, a3 = 0.f;
#pragma unroll
        for (int dc = 0; dc < 4; dc++) {
            float kc[8];
#pragma unroll
            for (int i = 0; i < 8; i++) kc[i] = kp[(dc * 8 + i) * 64];
#pragma unroll
            for (int i = 0; i < 8; i++) {
                a0 += q0[dc * 8 + i] * kc[i];
                a1 += q1[dc * 8 + i] * kc[i];
                a2 += q2[dc * 8 + i] * kc[i];
                a3 += q3[dc * 8 + i] * kc[i];
            }
        }
        a0 *= SCALE; a1 *= SCALE; a2 *= SCALE; a3 *= SCALE;
        if (PERSIST) {
            int j = kt * 64 + lane;
            aw0[j] = a0;
            aw1[j] = a1;
            aw2[j] = a2;
            aw3[j] = a3;
        }
        float e0 = __expf(a0), e1 = __expf(a1), e2 = __expf(a2), e3 = __expf(a3);
        S0 += e0; T0 += e0 * a0;
        S1 += e1; T1 += e1 * a1;
        S2 += e2; T2 += e2 * a2;
        S3 += e3; T3 += e3 * a3;
    }
#pragma unroll
    for (int o = 1; o < 64; o <<= 1) {
        S0 += __shfl_xor(S0, o); T0 += __shfl_xor(T0, o);
        S1 += __shfl_xor(S1, o); T1 += __shfl_xor(T1, o);
        S2 += __shfl_xor(S2, o); T2 += __shfl_xor(T2, o);
        S3 += __shfl_xor(S3, o); T3 += __shfl_xor(T3, o);
    }
    if (lane == 0) {
        size_t base = (size_t)bh * NN + row0 + lr0;
        ent[base + 0] = logf(S0) - T0 / S0;
        ent[base + 1] = logf(S1) - T1 / S1;
        ent[base + 2] = logf(S2) - T2 / S2;
        ent[base + 3] = logf(S3) - T3 / S3;
    }
}

// ---------- gate ----------
__global__ void gate_kernel(const float* __restrict__ ent_rows,
                            const float* __restrict__ g1w, const float* __restrict__ g1b,
                            const float* __restrict__ g2w, const float* __restrict__ g2b,
                            int* __restrict__ keep) {
    int bh = blockIdx.x;
    int tid = threadIdx.x;
    __shared__ float red[4];
    float ls = 0.f;
    for (int j = tid; j < NN; j += 256) ls += ent_rows[bh * NN + j];
    for (int o = 32; o > 0; o >>= 1) ls += __shfl_down(ls, o);
    int lane = tid & 63, wid = tid >> 6;
    if (lane == 0) red[wid] = ls;
    __syncthreads();
    if (tid == 0) {
        float ent = (red[0] + red[1] + red[2] + red[3]) / (float)NN;
        float val = g2b[0];
#pragma unroll
        for (int j = 0; j < 16; j++) {
            float hid = ent * g1w[j] + g1b[j];
            if (hid < 0.f) hid = 0.f;
            val += hid * g2w[j];
        }
        float ratio = 0.9f / (1.f + expf(-val)) + 0.1f;
        int kp = (int)ceilf(ratio * (float)NN);
        if (kp < 1) kp = 1;
        if (kp > NN) kp = NN;
        keep[bh] = kp;
    }
}

// ---------- select: 4 waves/block; f4-vectorized key loads (perm-invariant radix) ----------
__global__ __launch_bounds__(256, 4) void select_kernel(const float* __restrict__ attbuf,
                                                        const int* __restrict__ keep,
                                                        float* __restrict__ kth_out,
                                                        float* __restrict__ m_out) {
    int blk = blockIdx.x;                // bh*(NN/8) + rt
    int rt = blk % (NN / 8);
    int bh = blk / (NN / 8);
    int row0 = rt * 8;
    __shared__ unsigned hist[4][RTS][256];   // 8 KB
    int tid = threadIdx.x;
    int wv = tid >> 6;
    int lane = tid & 63;
    int wrow0 = row0 + 2 * wv;           // this wave's row pair
    int want = keep[bh];
    int l = lane & 31;
    int r = (lane < 32) ? 0 : 1;
    const float* ar = attbuf + ((size_t)bh * NN + wrow0 + r) * NN;

    // keys: f4-vectorized permutation of the row (radix/max are perm-invariant)
    unsigned kvr[50];
#pragma unroll
    for (int c = 0; c < 12; c++) {
        f4 v = *(const f4*)(ar + c * 128 + l * 4);
        kvr[c * 4 + 0] = fkey(v.x);
        kvr[c * 4 + 1] = fkey(v.y);
        kvr[c * 4 + 2] = fkey(v.z);
        kvr[c * 4 + 3] = fkey(v.w);
    }
    kvr[48] = fkey(ar[1536 + l * 2]);
    kvr[49] = fkey(ar[1536 + l * 2 + 1]);

    // row max via monotone keys (== fmax over the row)
    unsigned mk = 0u;
#pragma unroll
    for (int k2 = 0; k2 < 50; k2++) mk = mk > kvr[k2] ? mk : kvr[k2];
#pragma unroll
    for (int off = 1; off < 32; off <<= 1) {
        unsigned o = (unsigned)__shfl_xor((int)mk, off);
        mk = mk > o ? mk : o;
    }

    // ---- radix select kth-largest (R0-verbatim, hist per wave) ----
    unsigned prefixHigh = 0;
    for (int pass = 0; pass < 4; pass++) {
        int shift = 24 - 8 * pass;
#pragma unroll
        for (int i = 0; i < 8; i++) hist[wv][r][248 - 8 * l + i] = 0u;
#pragma unroll
        for (int k2 = 0; k2 < 50; k2++) {
            unsigned u = kvr[k2];
            bool ok = (pass == 0) || ((u >> (shift + 8)) == prefixHigh);
            if (ok) atomicAdd(&hist[wv][r][(u >> shift) & 255u], 1u);
        }
        unsigned sch = 0;
#pragma unroll
        for (int i = 0; i < 8; i++) sch += hist[wv][r][248 - 8 * l + i];
        unsigned inc = sch;
#pragma unroll
        for (int dlt = 1; dlt < 32; dlt <<= 1) {
            unsigned tv = __shfl_up(inc, dlt, 32);
            if (l >= dlt) inc += tv;
        }
        unsigned pref = inc - sch;
        bool found = (pref < (unsigned)want) && ((unsigned)want <= inc);
        int bsel = -1, wnew = 0;
        if (found) {
            unsigned want2 = (unsigned)want - pref, cum = 0;
#pragma unroll
            for (int i = 0; i < 8; i++) {
                int bbin = 255 - 8 * l - i;
                unsigned c = hist[wv][r][bbin];
                if (bsel < 0 && cum + c >= want2) { bsel = bbin; wnew = (int)(want2 - cum); }
                cum += c;
            }
        }
        unsigned long long mkb = __ballot(found);
        int src = (lane < 32) ? __builtin_ctzll(mkb & 0xffffffffULL)
                              : __builtin_ctzll(mkb >> 32) + 32;
        bsel = __shfl(bsel, src);
        want = __shfl(wnew, src);
        prefixHigh = (prefixHigh << 8) | (unsigned)bsel;
    }
    if (l == 0) {
        kth_out[(size_t)bh * NN + wrow0 + r] = finv(prefixHigh);
        m_out[(size_t)bh * NN + wrow0 + r] = finv(mk);
    }
}

// ---------- PV: 16 rows/block, 8 waves share one V double-buffer (V L2 traffic /2) ----------
__global__ __launch_bounds__(512) void pv_kernel(const float* __restrict__ qkv_t,
                                                 const float* __restrict__ attbuf,
                                                 const float* __restrict__ kth_in,
                                                 const float* __restrict__ m_in,
                                                 float* __restrict__ oht) {
    int blk = blockIdx.x;                // bh*(NN/16) + rt
    int rt = blk % (NN / 16);
    int bh = blk / (NN / 16);
    int h = bh % NHEADS, b = bh / NHEADS;
    int row0 = rt * 16;
    // [0..4095]: V double-buffer (2 x 2048); after final barrier reused as 8 x 1056 scratch
    __shared__ float lds[8448];          // 33.8 KB
    int tid = threadIdx.x;               // 0..511, 8 waves
    int wv = tid >> 6;
    int lane = tid & 63;
    int r0 = row0 + 2 * wv;
    const float* vtb = qkv_t + ((size_t)(b * 3 + 2) * NHEADS + h) * HSTR;
    const float* ab0 = attbuf + ((size_t)bh * NN + r0) * NN;
    const float* ab1 = ab0 + NN;
    float m0 = m_in[(size_t)bh * NN + r0];
    float m1 = m_in[(size_t)bh * NN + r0 + 1];
    float kth0 = kth_in[(size_t)bh * NN + r0];
    float kth1 = kth_in[(size_t)bh * NN + r0 + 1];

    float acc0[HD], acc1[HD];
#pragma unroll
    for (int d = 0; d < HD; d++) { acc0[d] = 0.f; acc1[d] = 0.f; }
    float S0 = 0.f, S1 = 0.f;

    // prologue: stage tile 0 into regs (512 threads x f4 = one 2048-float tile)
    f4 st0;
    {
        const f4* vp = (const f4*)vtb;
        st0 = vp[tid];
    }
    int cur = 0;
#pragma unroll 1
    for (int kt = 0; kt < 25; kt++) {
        // write staged tile kt into lds[cur]
        {
            f4* dst = (f4*)&lds[cur * 2048];
            dst[tid] = st0;
        }
        __syncthreads();
        // issue next-tile global loads (latency hides under compute)
        if (kt + 1 < 25) {
            const f4* vp = (const f4*)(vtb + (kt + 1) * TSTR);
            st0 = vp[tid];
        }
        // compute tile kt from lds[cur]
        const float* vb = &lds[cur * 2048];
        int j = kt * 64 + lane;
        float a0 = ab0[j];
        float a1 = ab1[j];
        float p0 = (a0 >= kth0) ? __expf(a0 - m0) : 0.f;
        float p1 = (a1 >= kth1) ? __expf(a1 - m1) : 0.f;
        S0 += p0; S1 += p1;
#pragma unroll
        for (int d = 0; d < HD; d++) {
            float vv = vb[d * 64 + lane];
            acc0[d] += p0 * vv;
            acc1[d] += p1 * vv;
        }
        cur ^= 1;
    }
#pragma unroll
    for (int off = 1; off < 64; off <<= 1) {
        S0 += __shfl_xor(S0, off);
        S1 += __shfl_xor(S1, off);
    }

    // ---- fold 64->32 lanes, then per-wave LDS scratch reduce (32x33, R10 order) ----
#pragma unroll
    for (int d = 0; d < HD; d++) {
        acc0[d] += __shfl_xor(acc0[d], 32);
        acc1[d] += __shfl_xor(acc1[d], 32);
    }
    __syncthreads();                     // all staging reads done; safe to reuse lds
    float* sc = &lds[wv * 1056];
    int dd = lane & 31;
    if (lane < 32) {
#pragma unroll
        for (int d = 0; d < HD; d++) sc[lane * 33 + d] = acc0[d];
    }
    float sum0 = 0.f;
#pragma unroll
    for (int jj = 0; jj < 32; jj++) sum0 += sc[jj * 33 + dd];
    if (lane < 32) {
#pragma unroll
        for (int d = 0; d < HD; d++) sc[lane * 33 + d] = acc1[d];
    }
    float sum1 = 0.f;
#pragma unroll
    for (int jj = 0; jj < 32; jj++) sum1 += sc[jj * 33 + dd];

    if (lane < 32) {
        size_t base = ((size_t)b * CDIM + h * HD + dd) * NN + r0;
        oht[base + 0] = sum0 / S0;
        oht[base + 1] = sum1 / S1;
    }
}

// ---------- fallback (no workspace for attbuf): R0 monolith ----------
__global__ __launch_bounds__(64) void sparse_attn_kernel(const float* __restrict__ qkv_t,
                                                         const int* __restrict__ keep,
                                                         float* __restrict__ oht) {
    int blk = blockIdx.x;
    int rt = blk % (NN / RTS);
    int bh = blk / (NN / RTS);
    int h = bh % NHEADS, b = bh / NHEADS;
    int row0 = rt * RTS;
    __shared__ float att[RTS][NN];
    __shared__ unsigned hist[RTS][256];
    __shared__ float Qs[RTS][HD];
    int tid = threadIdx.x;
    const float* qt = qkv_t + ((size_t)(b * 3 + 0) * NHEADS + h) * HSTR;
    const float* ktb = qkv_t + ((size_t)(b * 3 + 1) * NHEADS + h) * HSTR;
    const float* vtb = qkv_t + ((size_t)(b * 3 + 2) * NHEADS + h) * HSTR;
    {
        int r = tid >> 5, d = tid & 31;
        int row = row0 + r;
        Qs[r][d] = qt[(row >> 6) * TSTR + d * 64 + (row & 63)];
    }
    int want = keep[bh];
    __syncthreads();
    int lane = tid;
    float q0[HD], q1[HD];
#pragma unroll
    for (int d = 0; d < HD; d++) { q0[d] = Qs[0][d]; q1[d] = Qs[1][d]; }
    float m0 = -1e30f, m1 = -1e30f;
    for (int kt = 0; kt < 25; kt++) {
        const float* kp = ktb + kt * TSTR + lane;
        int j = kt * 64 + lane;
        float kc[HD];
#pragma unroll
        for (int d = 0; d < HD; d++) kc[d] = kp[d * 64];
        float a0 = 0.f, a1 = 0.f;
#pragma unroll
        for (int d = 0; d < HD; d++) { a0 += q0[d] * kc[d]; a1 += q1[d] * kc[d]; }
        a0 *= SCALE; a1 *= SCALE;
        att[0][j] = a0;
        att[1][j] = a1;
        m0 = fmaxf(m0, a0); m1 = fmaxf(m1, a1);
    }
#pragma unroll
    for (int off = 1; off < 64; off <<= 1) {
        m0 = fmaxf(m0, __shfl_xor(m0, off));
        m1 = fmaxf(m1, __shfl_xor(m1, off));
    }
    int l = lane & 31;
    int r = (lane < 32) ? 0 : 1;
    unsigned kvr[50];
#pragma unroll
    for (int k2 = 0; k2 < 50; k2++) kvr[k2] = fkey(att[r][k2 * 32 + l]);
    unsigned prefixHigh = 0;
    for (int pass = 0; pass < 4; pass++) {
        int shift = 24 - 8 * pass;
#pragma unroll
        for (int i = 0; i < 8; i++) hist[r][248 - 8 * l + i] = 0u;
#pragma unroll
        for (int k2 = 0; k2 < 50; k2++) {
            unsigned u = kvr[k2];
            bool ok = (pass == 0) || ((u >> (shift + 8)) == prefixHigh);
            if (ok) atomicAdd(&hist[r][(u >> shift) & 255u], 1u);
        }
        unsigned sch = 0;
#pragma unroll
        for (int i = 0; i < 8; i++) sch += hist[r][248 - 8 * l + i];
        unsigned inc = sch;
#pragma unroll
        for (int dlt = 1; dlt < 32; dlt <<= 1) {
            unsigned tv = __shfl_up(inc, dlt, 32);
            if (l >= dlt) inc += tv;
        }
        unsigned pref = inc - sch;
        bool found = (pref < (unsigned)want) && ((unsigned)want <= inc);
        int bsel = -1, wnew = 0;
        if (found) {
            unsigned want2 = (unsigned)want - pref, cum = 0;
#pragma unroll
            for (int i = 0; i < 8; i++) {
                int bbin = 255 - 8 * l - i;
                unsigned c = hist[r][bbin];
                if (bsel < 0 && cum + c >= want2) { bsel = bbin; wnew = (int)(want2 - cum); }
                cum += c;
            }
        }
        unsigned long long mk = __ballot(found);
        int src = (lane < 32) ? __builtin_ctzll(mk & 0xffffffffULL)
                              : __builtin_ctzll(mk >> 32) + 32;
        bsel = __shfl(bsel, src);
        want = __shfl(wnew, src);
        prefixHigh = (prefixHigh << 8) | (unsigned)bsel;
    }
    float kth = finv(prefixHigh);
    float kth0 = __shfl(kth, 0);
    float kth1 = __shfl(kth, 32);
    float acc0[HD], acc1[HD];
#pragma unroll
    for (int d = 0; d < HD; d++) { acc0[d] = 0.f; acc1[d] = 0.f; }
    float S0 = 0.f, S1 = 0.f;
    for (int kt = 0; kt < 25; kt++) {
        const float* vp = vtb + kt * TSTR + lane;
        int j = kt * 64 + lane;
        float a0 = att[0][j];
        float a1 = att[1][j];
        float p0 = (a0 >= kth0) ? __expf(a0 - m0) : 0.f;
        float p1 = (a1 >= kth1) ? __expf(a1 - m1) : 0.f;
        S0 += p0; S1 += p1;
#pragma unroll
        for (int d = 0; d < HD; d++) {
            float vv = vp[d * 64];
            acc0[d] += p0 * vv;
            acc1[d] += p1 * vv;
        }
    }
#pragma unroll
    for (int off = 1; off < 64; off <<= 1) {
        S0 += __shfl_xor(S0, off);
        S1 += __shfl_xor(S1, off);
    }
    float* scratch = &att[0][0];
    int dd = lane & 31;
    int jb = (lane < 32) ? 0 : 32;
#pragma unroll
    for (int d = 0; d < HD; d++) scratch[lane * 33 + d] = acc0[d];
    float sum0 = 0.f;
#pragma unroll
    for (int jj = 0; jj < 32; jj++) sum0 += scratch[(jb + jj) * 33 + dd];
    sum0 += __shfl_xor(sum0, 32);
#pragma unroll
    for (int d = 0; d < HD; d++) scratch[lane * 33 + d] = acc1[d];
    float sum1 = 0.f;
#pragma unroll
    for (int jj = 0; jj < 32; jj++) sum1 += scratch[(jb + jj) * 33 + dd];
    sum1 += __shfl_xor(sum1, 32);
    if (lane < 32) {
        size_t base = ((size_t)b * CDIM + h * HD + dd) * NN + row0;
        oht[base + 0] = sum0 / S0;
        oht[base + 1] = sum1 / S1;
    }
}

// ---------- output projection from oht [b][c][n]: 8 oc per thread ----------
__global__ __launch_bounds__(256) void proj_kernel(const float* __restrict__ oht,
                                                   const float* __restrict__ pw,
                                                   const float* __restrict__ pb,
                                                   float* __restrict__ out) {
    int blk = blockIdx.x;
    int st = blk % 7;
    int t2 = blk / 7;
    int ocg = t2 % (CDIM / 8);
    int b = t2 / (CDIM / 8);
    int s = st * 256 + threadIdx.x;
    if (s >= NN) return;
    int co0 = ocg * 8;
    const float* ib = oht + (size_t)b * CDIM * NN + s;
    const float* w0 = pw + (size_t)co0 * CDIM;
    float a[8];
#pragma unroll
    for (int i = 0; i < 8; i++) a[i] = pb[co0 + i];
#pragma unroll 4
    for (int c = 0; c < CDIM; c++) {
        float xv = ib[(size_t)c * NN];
#pragma unroll
        for (int i = 0; i < 8; i++) a[i] += w0[i * CDIM + c] * xv;
    }
    float* ob = out + ((size_t)b * CDIM + co0) * NN + s;
#pragma unroll
    for (int i = 0; i < 8; i++) ob[(size_t)i * NN] = a[i];
}

extern "C" void kernel_launch(void* const* d_in, const int* in_sizes, int n_in,
                              void* d_out, int out_size, void* d_ws, size_t ws_size,
                              hipStream_t stream) {
    const float* x      = (const float*)d_in[0];
    const float* qkv_w  = (const float*)d_in[1];
    const float* qkv_b  = (const float*)d_in[2];
    const float* pos_w  = (const float*)d_in[3];
    const float* pos_b  = (const float*)d_in[4];
    const float* proj_w = (const float*)d_in[5];
    const float* proj_b = (const float*)d_in[6];
    const float* g1w    = (const float*)d_in[7];
    const float* g1b    = (const float*)d_in[8];
    const float* g2w    = (const float*)d_in[9];
    const float* g2b    = (const float*)d_in[10];
    float* out = (float*)d_out;

    float* ws   = (float*)d_ws;
    float* buf1 = ws;                                  // BB*C3*NN  ([b][c][s])
    float* buf2 = buf1 + (size_t)BB * C3 * NN;         // BB*C3*NN  (j-tiled)
    float* ent  = buf2 + (size_t)BB * C3 * NN;         // BB*NHEADS*NN
    float* oht  = ent + (size_t)BB * NHEADS * NN;      // BB*CDIM*NN  ([b][c][n])
    int* keep   = (int*)(oht + (size_t)BB * CDIM * NN);
    float* kth  = (float*)(keep + 16);                 // BB*NHEADS*NN
    float* mrow = kth + (size_t)BB * NHEADS * NN;      // BB*NHEADS*NN
    float* attbuf = mrow + (size_t)BB * NHEADS * NN;   // BB*NHEADS*NN*NN (163.8 MB)
    size_t need = (size_t)((char*)(attbuf + (size_t)BB * NHEADS * NN * NN) - (char*)d_ws);
    bool persist = (ws_size >= need);

    conv1x1_kernel<<<BB * (C3 / 8) * 7, 256, 0, stream>>>(x, qkv_w, qkv_b, buf1);
    dwconv_kernel<<<BB * C3 * NN / 256, 256, 0, stream>>>(buf1, pos_w, pos_b, buf2);
    if (persist) {
        entropy_kernel<1><<<NHEADS * BB * (NN / RTE), 256, 0, stream>>>(buf2, ent, attbuf);
        gate_kernel<<<BB * NHEADS, 256, 0, stream>>>(ent, g1w, g1b, g2w, g2b, keep);
        select_kernel<<<NHEADS * BB * (NN / 8), 256, 0, stream>>>(attbuf, keep, kth, mrow);
        pv_kernel<<<NHEADS * BB * (NN / 16), 512, 0, stream>>>(buf2, attbuf, kth, mrow, oht);
    } else {
        entropy_kernel<0><<<NHEADS * BB * (NN / RTE), 256, 0, stream>>>(buf2, ent, nullptr);
        gate_kernel<<<BB * NHEADS, 256, 0, stream>>>(ent, g1w, g1b, g2w, g2b, keep);
        sparse_attn_kernel<<<NHEADS * BB * (NN / RTS), 64, 0, stream>>>(buf2, keep, oht);
    }
    proj_kernel<<<BB * (CDIM / 8) * 7, 256, 0, stream>>>(oht, proj_w, proj_b, out);
}

// Round 17
// 392.074 us; speedup vs baseline: 1.1200x; 1.1200x over previous
//
#include <hip/hip_runtime.h>
#include <math.h>

#define BB 2
#define CDIM 256
#define NHEADS 8
#define HD 32
#define HH 40
#define WW 40
#define NN 1600
#define C3 768
#define SCALE 0.17677669529663687f  // 1/sqrt(32)
#define RTE 16           // rows per block, entropy kernel (4 per wave)
#define RTS 2            // rows per block, fallback sparse kernel (1 wave)
#define TSTR 2048        // tile stride: 32 d * 64 jl
#define HSTR 51200       // per (b,part,h): 25 tiles * 2048

typedef __attribute__((ext_vector_type(4))) float f4;

// ---------- helpers ----------
__device__ inline unsigned fkey(float f) {
    unsigned u = __float_as_uint(f);
    return (u & 0x80000000u) ? ~u : (u | 0x80000000u);
}
__device__ inline float finv(unsigned u) {
    unsigned v = (u & 0x80000000u) ? (u ^ 0x80000000u) : ~u;
    return __uint_as_float(v);
}

// ---------- 1x1 conv: 8 output channels per thread ----------
__global__ __launch_bounds__(256) void conv1x1_kernel(const float* __restrict__ x,
                                                      const float* __restrict__ w,
                                                      const float* __restrict__ bias,
                                                      float* __restrict__ out) {
    int blk = blockIdx.x;
    int st = blk % 7;
    int t2 = blk / 7;
    int ocg = t2 % (C3 / 8);
    int b = t2 / (C3 / 8);
    int s = st * 256 + threadIdx.x;
    if (s >= NN) return;
    int oc0 = ocg * 8;
    const float* xb = x + (size_t)b * CDIM * NN + s;
    const float* w0 = w + (size_t)oc0 * CDIM;
    float a[8];
#pragma unroll
    for (int i = 0; i < 8; i++) a[i] = bias[oc0 + i];
#pragma unroll 4
    for (int ic = 0; ic < CDIM; ic++) {
        float xv = xb[(size_t)ic * NN];
#pragma unroll
        for (int i = 0; i < 8; i++) a[i] += w0[i * CDIM + ic] * xv;
    }
    float* ob = out + ((size_t)b * C3 + oc0) * NN + s;
#pragma unroll
    for (int i = 0; i < 8; i++) ob[(size_t)i * NN] = a[i];
}

// ---------- depthwise 3x3 pad1; writes j-tiled layout [b][part][h][kt][d][jl] ----------
__global__ __launch_bounds__(256) void dwconv_kernel(const float* __restrict__ in,
                                                     const float* __restrict__ w,
                                                     const float* __restrict__ bias,
                                                     float* __restrict__ out_t) {
    int idx = blockIdx.x * 256 + threadIdx.x;
    int s = idx % NN;
    int t = idx / NN;
    int c = t % C3;
    int b = t / C3;
    int y = s / WW, xx = s % WW;
    const float* ib = in + ((size_t)b * C3 + c) * NN;
    const float* wr = w + (size_t)c * 9;
    float acc = bias[c];
#pragma unroll
    for (int ky = 0; ky < 3; ky++) {
        int iy = y + ky - 1;
        if (iy < 0 || iy >= HH) continue;
#pragma unroll
        for (int kx = 0; kx < 3; kx++) {
            int ix = xx + kx - 1;
            if (ix < 0 || ix >= WW) continue;
            acc += wr[ky * 3 + kx] * ib[iy * WW + ix];
        }
    }
    int part = c >> 8;
    int r = c & 255;
    int hh = r >> 5;
    int d = r & 31;
    out_t[((size_t)(b * 3 + part) * NHEADS + hh) * HSTR + (s >> 6) * TSTR + d * 64 + (s & 63)] = acc;
}

// ---------- phase 1: streaming entropy, 4 rows per wave; optional attbuf persist ----------
template <int PERSIST>
__global__ __launch_bounds__(256) void entropy_kernel(const float* __restrict__ qkv_t,
                                                      float* __restrict__ ent,
                                                      float* __restrict__ attw) {
    int blk = blockIdx.x;      // bh*(NN/RTE) + rt
    int rt = blk % (NN / RTE);
    int bh = blk / (NN / RTE);
    int h = bh % NHEADS, b = bh / NHEADS;
    int row0 = rt * RTE;
    __shared__ float Qs[RTE][HD];
    int tid = threadIdx.x;
    const float* qt = qkv_t + ((size_t)(b * 3 + 0) * NHEADS + h) * HSTR;
    const float* ktb = qkv_t + ((size_t)(b * 3 + 1) * NHEADS + h) * HSTR;
#pragma unroll
    for (int i = tid; i < RTE * HD; i += 256) {
        int r = i >> 5, d = i & 31;
        int row = row0 + r;
        Qs[r][d] = qt[(row >> 6) * TSTR + d * 64 + (row & 63)];
    }
    __syncthreads();
    int w = tid >> 6, lane = tid & 63;
    int lr0 = 4 * w;                     // this wave's 4 rows
    float* aw0 = nullptr; float* aw1 = nullptr; float* aw2 = nullptr; float* aw3 = nullptr;
    if (PERSIST) {
        aw0 = attw + ((size_t)bh * NN + row0 + lr0) * NN;
        aw1 = aw0 + NN;
        aw2 = aw1 + NN;
        aw3 = aw2 + NN;
    }
    float q0[HD], q1[HD], q2[HD], q3[HD];
#pragma unroll
    for (int d = 0; d < HD; d++) {
        q0[d] = Qs[lr0 + 0][d];
        q1[d] = Qs[lr0 + 1][d];
        q2[d] = Qs[lr0 + 2][d];
        q3[d] = Qs[lr0 + 3][d];
    }
    float S0 = 0.f, T0 = 0.f, S1 = 0.f, T1 = 0.f;
    float S2 = 0.f, T2 = 0.f, S3 = 0.f, T3 = 0.f;
#pragma unroll 1
    for (int kt = 0; kt < 25; kt++) {
        const float* kp = ktb + kt * TSTR + lane;
        float a0 = 0.f, a1 = 0.f, a2 = 0.f, a3 = 0.f;
#pragma unroll
        for (int dc = 0; dc < 4; dc++) {
            float kc[8];
#pragma unroll
            for (int i = 0; i < 8; i++) kc[i] = kp[(dc * 8 + i) * 64];
#pragma unroll
            for (int i = 0; i < 8; i++) {
                a0 += q0[dc * 8 + i] * kc[i];
                a1 += q1[dc * 8 + i] * kc[i];
                a2 += q2[dc * 8 + i] * kc[i];
                a3 += q3[dc * 8 + i] * kc[i];
            }
        }
        a0 *= SCALE; a1 *= SCALE; a2 *= SCALE; a3 *= SCALE;
        if (PERSIST) {
            int j = kt * 64 + lane;
            aw0[j] = a0;
            aw1[j] = a1;
            aw2[j] = a2;
            aw3[j] = a3;
        }
        float e0 = __expf(a0), e1 = __expf(a1), e2 = __expf(a2), e3 = __expf(a3);
        S0 += e0; T0 += e0 * a0;
        S1 += e1; T1 += e1 * a1;
        S2 += e2; T2 += e2 * a2;
        S3 += e3; T3 += e3 * a3;
    }
#pragma unroll
    for (int o = 1; o < 64; o <<= 1) {
        S0 += __shfl_xor(S0, o); T0 += __shfl_xor(T0, o);
        S1 += __shfl_xor(S1, o); T1 += __shfl_xor(T1, o);
        S2 += __shfl_xor(S2, o); T2 += __shfl_xor(T2, o);
        S3 += __shfl_xor(S3, o); T3 += __shfl_xor(T3, o);
    }
    if (lane == 0) {
        size_t base = (size_t)bh * NN + row0 + lr0;
        ent[base + 0] = logf(S0) - T0 / S0;
        ent[base + 1] = logf(S1) - T1 / S1;
        ent[base + 2] = logf(S2) - T2 / S2;
        ent[base + 3] = logf(S3) - T3 / S3;
    }
}

// ---------- gate ----------
__global__ void gate_kernel(const float* __restrict__ ent_rows,
                            const float* __restrict__ g1w, const float* __restrict__ g1b,
                            const float* __restrict__ g2w, const float* __restrict__ g2b,
                            int* __restrict__ keep) {
    int bh = blockIdx.x;
    int tid = threadIdx.x;
    __shared__ float red[4];
    float ls = 0.f;
    for (int j = tid; j < NN; j += 256) ls += ent_rows[bh * NN + j];
    for (int o = 32; o > 0; o >>= 1) ls += __shfl_down(ls, o);
    int lane = tid & 63, wid = tid >> 6;
    if (lane == 0) red[wid] = ls;
    __syncthreads();
    if (tid == 0) {
        float ent = (red[0] + red[1] + red[2] + red[3]) / (float)NN;
        float val = g2b[0];
#pragma unroll
        for (int j = 0; j < 16; j++) {
            float hid = ent * g1w[j] + g1b[j];
            if (hid < 0.f) hid = 0.f;
            val += hid * g2w[j];
        }
        float ratio = 0.9f / (1.f + expf(-val)) + 0.1f;
        int kp = (int)ceilf(ratio * (float)NN);
        if (kp < 1) kp = 1;
        if (kp > NN) kp = NN;
        keep[bh] = kp;
    }
}

// ---------- select: 4 waves/block, one row-pair per wave; R0-verbatim radix ----------
__global__ __launch_bounds__(256, 4) void select_kernel(const float* __restrict__ attbuf,
                                                        const int* __restrict__ keep,
                                                        float* __restrict__ kth_out,
                                                        float* __restrict__ m_out) {
    int blk = blockIdx.x;                // bh*(NN/8) + rt
    int rt = blk % (NN / 8);
    int bh = blk / (NN / 8);
    int row0 = rt * 8;
    __shared__ unsigned hist[4][RTS][256];   // 8 KB
    int tid = threadIdx.x;
    int wv = tid >> 6;
    int lane = tid & 63;
    int wrow0 = row0 + 2 * wv;           // this wave's row pair
    int want = keep[bh];
    int l = lane & 31;
    int r = (lane < 32) ? 0 : 1;
    const float* ar = attbuf + ((size_t)bh * NN + wrow0 + r) * NN;

    // keys: 32 lanes per row, 50 keys/lane (same layout as R0's kvr)
    unsigned kvr[50];
#pragma unroll
    for (int k2 = 0; k2 < 50; k2++) kvr[k2] = fkey(ar[k2 * 32 + l]);

    // row max via monotone keys (== fmax over the row)
    unsigned mk = 0u;
#pragma unroll
    for (int k2 = 0; k2 < 50; k2++) mk = mk > kvr[k2] ? mk : kvr[k2];
#pragma unroll
    for (int off = 1; off < 32; off <<= 1) {
        unsigned o = (unsigned)__shfl_xor((int)mk, off);
        mk = mk > o ? mk : o;
    }

    // ---- radix select kth-largest (R0-verbatim, hist per wave) ----
    unsigned prefixHigh = 0;
    for (int pass = 0; pass < 4; pass++) {
        int shift = 24 - 8 * pass;
#pragma unroll
        for (int i = 0; i < 8; i++) hist[wv][r][248 - 8 * l + i] = 0u;
#pragma unroll
        for (int k2 = 0; k2 < 50; k2++) {
            unsigned u = kvr[k2];
            bool ok = (pass == 0) || ((u >> (shift + 8)) == prefixHigh);
            if (ok) atomicAdd(&hist[wv][r][(u >> shift) & 255u], 1u);
        }
        unsigned sch = 0;
#pragma unroll
        for (int i = 0; i < 8; i++) sch += hist[wv][r][248 - 8 * l + i];
        unsigned inc = sch;
#pragma unroll
        for (int dlt = 1; dlt < 32; dlt <<= 1) {
            unsigned tv = __shfl_up(inc, dlt, 32);
            if (l >= dlt) inc += tv;
        }
        unsigned pref = inc - sch;
        bool found = (pref < (unsigned)want) && ((unsigned)want <= inc);
        int bsel = -1, wnew = 0;
        if (found) {
            unsigned want2 = (unsigned)want - pref, cum = 0;
#pragma unroll
            for (int i = 0; i < 8; i++) {
                int bbin = 255 - 8 * l - i;
                unsigned c = hist[wv][r][bbin];
                if (bsel < 0 && cum + c >= want2) { bsel = bbin; wnew = (int)(want2 - cum); }
                cum += c;
            }
        }
        unsigned long long mkb = __ballot(found);
        int src = (lane < 32) ? __builtin_ctzll(mkb & 0xffffffffULL)
                              : __builtin_ctzll(mkb >> 32) + 32;
        bsel = __shfl(bsel, src);
        want = __shfl(wnew, src);
        prefixHigh = (prefixHigh << 8) | (unsigned)bsel;
    }
    if (l == 0) {
        kth_out[(size_t)bh * NN + wrow0 + r] = finv(prefixHigh);
        m_out[(size_t)bh * NN + wrow0 + r] = finv(mk);
    }
}

// ---------- PV: R10-exact (V LDS double-buffer, single-barrier phases) ----------
__global__ __launch_bounds__(256, 4) void pv_kernel(const float* __restrict__ qkv_t,
                                                    const float* __restrict__ attbuf,
                                                    const float* __restrict__ kth_in,
                                                    const float* __restrict__ m_in,
                                                    float* __restrict__ oht) {
    int blk = blockIdx.x;                // bh*(NN/8) + rt
    int rt = blk % (NN / 8);
    int bh = blk / (NN / 8);
    int h = bh % NHEADS, b = bh / NHEADS;
    int row0 = rt * 8;
    // [0..4095]: V double-buffer (2 x 2048 floats); reused at end as 4 x 1056 reduce scratch
    __shared__ float lds[4224];          // 16.9 KB
    int tid = threadIdx.x;
    int wv = tid >> 6;
    int lane = tid & 63;
    int r0 = row0 + 2 * wv;
    const float* vtb = qkv_t + ((size_t)(b * 3 + 2) * NHEADS + h) * HSTR;
    const float* ab0 = attbuf + ((size_t)bh * NN + r0) * NN;
    const float* ab1 = ab0 + NN;
    float m0 = m_in[(size_t)bh * NN + r0];
    float m1 = m_in[(size_t)bh * NN + r0 + 1];
    float kth0 = kth_in[(size_t)bh * NN + r0];
    float kth1 = kth_in[(size_t)bh * NN + r0 + 1];

    float acc0[HD], acc1[HD];
#pragma unroll
    for (int d = 0; d < HD; d++) { acc0[d] = 0.f; acc1[d] = 0.f; }
    float S0 = 0.f, S1 = 0.f;

    // prologue: stage tile 0 into regs
    f4 st0, st1;
    {
        const f4* vp = (const f4*)vtb;
        st0 = vp[tid];
        st1 = vp[256 + tid];
    }
    int cur = 0;
#pragma unroll 1
    for (int kt = 0; kt < 25; kt++) {
        // write staged tile kt into lds[cur]
        {
            f4* dst = (f4*)&lds[cur * 2048];
            dst[tid] = st0;
            dst[256 + tid] = st1;
        }
        __syncthreads();
        // issue next-tile global loads (latency hides under compute)
        if (kt + 1 < 25) {
            const f4* vp = (const f4*)(vtb + (kt + 1) * TSTR);
            st0 = vp[tid];
            st1 = vp[256 + tid];
        }
        // compute tile kt from lds[cur]
        const float* vb = &lds[cur * 2048];
        int j = kt * 64 + lane;
        float a0 = ab0[j];
        float a1 = ab1[j];
        float p0 = (a0 >= kth0) ? __expf(a0 - m0) : 0.f;
        float p1 = (a1 >= kth1) ? __expf(a1 - m1) : 0.f;
        S0 += p0; S1 += p1;
#pragma unroll
        for (int d = 0; d < HD; d++) {
            float vv = vb[d * 64 + lane];
            acc0[d] += p0 * vv;
            acc1[d] += p1 * vv;
        }
        cur ^= 1;
    }
#pragma unroll
    for (int off = 1; off < 64; off <<= 1) {
        S0 += __shfl_xor(S0, off);
        S1 += __shfl_xor(S1, off);
    }

    // ---- fold 64->32 lanes, then per-wave LDS scratch reduce (32x33) ----
#pragma unroll
    for (int d = 0; d < HD; d++) {
        acc0[d] += __shfl_xor(acc0[d], 32);
        acc1[d] += __shfl_xor(acc1[d], 32);
    }
    __syncthreads();                     // all staging reads done; safe to reuse lds
    float* sc = &lds[wv * 1056];
    int dd = lane & 31;
    if (lane < 32) {
#pragma unroll
        for (int d = 0; d < HD; d++) sc[lane * 33 + d] = acc0[d];
    }
    float sum0 = 0.f;
#pragma unroll
    for (int jj = 0; jj < 32; jj++) sum0 += sc[jj * 33 + dd];
    if (lane < 32) {
#pragma unroll
        for (int d = 0; d < HD; d++) sc[lane * 33 + d] = acc1[d];
    }
    float sum1 = 0.f;
#pragma unroll
    for (int jj = 0; jj < 32; jj++) sum1 += sc[jj * 33 + dd];

    if (lane < 32) {
        size_t base = ((size_t)b * CDIM + h * HD + dd) * NN + r0;
        oht[base + 0] = sum0 / S0;
        oht[base + 1] = sum1 / S1;
    }
}

// ---------- fallback (no workspace for attbuf): R0 monolith ----------
__global__ __launch_bounds__(64) void sparse_attn_kernel(const float* __restrict__ qkv_t,
                                                         const int* __restrict__ keep,
                                                         float* __restrict__ oht) {
    int blk = blockIdx.x;
    int rt = blk % (NN / RTS);
    int bh = blk / (NN / RTS);
    int h = bh % NHEADS, b = bh / NHEADS;
    int row0 = rt * RTS;
    __shared__ float att[RTS][NN];
    __shared__ unsigned hist[RTS][256];
    __shared__ float Qs[RTS][HD];
    int tid = threadIdx.x;
    const float* qt = qkv_t + ((size_t)(b * 3 + 0) * NHEADS + h) * HSTR;
    const float* ktb = qkv_t + ((size_t)(b * 3 + 1) * NHEADS + h) * HSTR;
    const float* vtb = qkv_t + ((size_t)(b * 3 + 2) * NHEADS + h) * HSTR;
    {
        int r = tid >> 5, d = tid & 31;
        int row = row0 + r;
        Qs[r][d] = qt[(row >> 6) * TSTR + d * 64 + (row & 63)];
    }
    int want = keep[bh];
    __syncthreads();
    int lane = tid;
    float q0[HD], q1[HD];
#pragma unroll
    for (int d = 0; d < HD; d++) { q0[d] = Qs[0][d]; q1[d] = Qs[1][d]; }
    float m0 = -1e30f, m1 = -1e30f;
    for (int kt = 0; kt < 25; kt++) {
        const float* kp = ktb + kt * TSTR + lane;
        int j = kt * 64 + lane;
        float kc[HD];
#pragma unroll
        for (int d = 0; d < HD; d++) kc[d] = kp[d * 64];
        float a0 = 0.f, a1 = 0.f;
#pragma unroll
        for (int d = 0; d < HD; d++) { a0 += q0[d] * kc[d]; a1 += q1[d] * kc[d]; }
        a0 *= SCALE; a1 *= SCALE;
        att[0][j] = a0;
        att[1][j] = a1;
        m0 = fmaxf(m0, a0); m1 = fmaxf(m1, a1);
    }
#pragma unroll
    for (int off = 1; off < 64; off <<= 1) {
        m0 = fmaxf(m0, __shfl_xor(m0, off));
        m1 = fmaxf(m1, __shfl_xor(m1, off));
    }
    int l = lane & 31;
    int r = (lane < 32) ? 0 : 1;
    unsigned kvr[50];
#pragma unroll
    for (int k2 = 0; k2 < 50; k2++) kvr[k2] = fkey(att[r][k2 * 32 + l]);
    unsigned prefixHigh = 0;
    for (int pass = 0; pass < 4; pass++) {
        int shift = 24 - 8 * pass;
#pragma unroll
        for (int i = 0; i < 8; i++) hist[r][248 - 8 * l + i] = 0u;
#pragma unroll
        for (int k2 = 0; k2 < 50; k2++) {
            unsigned u = kvr[k2];
            bool ok = (pass == 0) || ((u >> (shift + 8)) == prefixHigh);
            if (ok) atomicAdd(&hist[r][(u >> shift) & 255u], 1u);
        }
        unsigned sch = 0;
#pragma unroll
        for (int i = 0; i < 8; i++) sch += hist[r][248 - 8 * l + i];
        unsigned inc = sch;
#pragma unroll
        for (int dlt = 1; dlt < 32; dlt <<= 1) {
            unsigned tv = __shfl_up(inc, dlt, 32);
            if (l >= dlt) inc += tv;
        }
        unsigned pref = inc - sch;
        bool found = (pref < (unsigned)want) && ((unsigned)want <= inc);
        int bsel = -1, wnew = 0;
        if (found) {
            unsigned want2 = (unsigned)want - pref, cum = 0;
#pragma unroll
            for (int i = 0; i < 8; i++) {
                int bbin = 255 - 8 * l - i;
                unsigned c = hist[r][bbin];
                if (bsel < 0 && cum + c >= want2) { bsel = bbin; wnew = (int)(want2 - cum); }
                cum += c;
            }
        }
        unsigned long long mk = __ballot(found);
        int src = (lane < 32) ? __builtin_ctzll(mk & 0xffffffffULL)
                              : __builtin_ctzll(mk >> 32) + 32;
        bsel = __shfl(bsel, src);
        want = __shfl(wnew, src);
        prefixHigh = (prefixHigh << 8) | (unsigned)bsel;
    }
    float kth = finv(prefixHigh);
    float kth0 = __shfl(kth, 0);
    float kth1 = __shfl(kth, 32);
    float acc0[HD], acc1[HD];
#pragma unroll
    for (int d = 0; d < HD; d++) { acc0[d] = 0.f; acc1[d] = 0.f; }
    float S0 = 0.f, S1 = 0.f;
    for (int kt = 0; kt < 25; kt++) {
        const float* vp = vtb + kt * TSTR + lane;
        int j = kt * 64 + lane;
        float a0 = att[0][j];
        float a1 = att[1][j];
        float p0 = (a0 >= kth0) ? __expf(a0 - m0) : 0.f;
        float p1 = (a1 >= kth1) ? __expf(a1 - m1) : 0.f;
        S0 += p0; S1 += p1;
#pragma unroll
        for (int d = 0; d < HD; d++) {
            float vv = vp[d * 64];
            acc0[d] += p0 * vv;
            acc1[d] += p1 * vv;
        }
    }
#pragma unroll
    for (int off = 1; off < 64; off <<= 1) {
        S0 += __shfl_xor(S0, off);
        S1 += __shfl_xor(S1, off);
    }
    float* scratch = &att[0][0];
    int dd = lane & 31;
    int jb = (lane < 32) ? 0 : 32;
#pragma unroll
    for (int d = 0; d < HD; d++) scratch[lane * 33 + d] = acc0[d];
    float sum0 = 0.f;
#pragma unroll
    for (int jj = 0; jj < 32; jj++) sum0 += scratch[(jb + jj) * 33 + dd];
    sum0 += __shfl_xor(sum0, 32);
#pragma unroll
    for (int d = 0; d < HD; d++) scratch[lane * 33 + d] = acc1[d];
    float sum1 = 0.f;
#pragma unroll
    for (int jj = 0; jj < 32; jj++) sum1 += scratch[(jb + jj) * 33 + dd];
    sum1 += __shfl_xor(sum1, 32);
    if (lane < 32) {
        size_t base = ((size_t)b * CDIM + h * HD + dd) * NN + row0;
        oht[base + 0] = sum0 / S0;
        oht[base + 1] = sum1 / S1;
    }
}

// ---------- output projection from oht [b][c][n]: 8 oc per thread ----------
__global__ __launch_bounds__(256) void proj_kernel(const float* __restrict__ oht,
                                                   const float* __restrict__ pw,
                                                   const float* __restrict__ pb,
                                                   float* __restrict__ out) {
    int blk = blockIdx.x;
    int st = blk % 7;
    int t2 = blk / 7;
    int ocg = t2 % (CDIM / 8);
    int b = t2 / (CDIM / 8);
    int s = st * 256 + threadIdx.x;
    if (s >= NN) return;
    int co0 = ocg * 8;
    const float* ib = oht + (size_t)b * CDIM * NN + s;
    const float* w0 = pw + (size_t)co0 * CDIM;
    float a[8];
#pragma unroll
    for (int i = 0; i < 8; i++) a[i] = pb[co0 + i];
#pragma unroll 4
    for (int c = 0; c < CDIM; c++) {
        float xv = ib[(size_t)c * NN];
#pragma unroll
        for (int i = 0; i < 8; i++) a[i] += w0[i * CDIM + c] * xv;
    }
    float* ob = out + ((size_t)b * CDIM + co0) * NN + s;
#pragma unroll
    for (int i = 0; i < 8; i++) ob[(size_t)i * NN] = a[i];
}

extern "C" void kernel_launch(void* const* d_in, const int* in_sizes, int n_in,
                              void* d_out, int out_size, void* d_ws, size_t ws_size,
                              hipStream_t stream) {
    const float* x      = (const float*)d_in[0];
    const float* qkv_w  = (const float*)d_in[1];
    const float* qkv_b  = (const float*)d_in[2];
    const float* pos_w  = (const float*)d_in[3];
    const float* pos_b  = (const float*)d_in[4];
    const float* proj_w = (const float*)d_in[5];
    const float* proj_b = (const float*)d_in[6];
    const float* g1w    = (const float*)d_in[7];
    const float* g1b    = (const float*)d_in[8];
    const float* g2w    = (const float*)d_in[9];
    const float* g2b    = (const float*)d_in[10];
    float* out = (float*)d_out;

    float* ws   = (float*)d_ws;
    float* buf1 = ws;                                  // BB*C3*NN  ([b][c][s])
    float* buf2 = buf1 + (size_t)BB * C3 * NN;         // BB*C3*NN  (j-tiled)
    float* ent  = buf2 + (size_t)BB * C3 * NN;         // BB*NHEADS*NN
    float* oht  = ent + (size_t)BB * NHEADS * NN;      // BB*CDIM*NN  ([b][c][n])
    int* keep   = (int*)(oht + (size_t)BB * CDIM * NN);
    float* kth  = (float*)(keep + 16);                 // BB*NHEADS*NN
    float* mrow = kth + (size_t)BB * NHEADS * NN;      // BB*NHEADS*NN
    float* attbuf = mrow + (size_t)BB * NHEADS * NN;   // BB*NHEADS*NN*NN (163.8 MB)
    size_t need = (size_t)((char*)(attbuf + (size_t)BB * NHEADS * NN * NN) - (char*)d_ws);
    bool persist = (ws_size >= need);

    conv1x1_kernel<<<BB * (C3 / 8) * 7, 256, 0, stream>>>(x, qkv_w, qkv_b, buf1);
    dwconv_kernel<<<BB * C3 * NN / 256, 256, 0, stream>>>(buf1, pos_w, pos_b, buf2);
    if (persist) {
        entropy_kernel<1><<<NHEADS * BB * (NN / RTE), 256, 0, stream>>>(buf2, ent, attbuf);
        gate_kernel<<<BB * NHEADS, 256, 0, stream>>>(ent, g1w, g1b, g2w, g2b, keep);
        select_kernel<<<NHEADS * BB * (NN / 8), 256, 0, stream>>>(attbuf, keep, kth, mrow);
        pv_kernel<<<NHEADS * BB * (NN / 8), 256, 0, stream>>>(buf2, attbuf, kth, mrow, oht);
    } else {
        entropy_kernel<0><<<NHEADS * BB * (NN / RTE), 256, 0, stream>>>(buf2, ent, nullptr);
        gate_kernel<<<BB * NHEADS, 256, 0, stream>>>(ent, g1w, g1b, g2w, g2b, keep);
        sparse_attn_kernel<<<NHEADS * BB * (NN / RTS), 64, 0, stream>>>(buf2, keep, oht);
    }
    proj_kernel<<<BB * (CDIM / 8) * 7, 256, 0, stream>>>(oht, proj_w, proj_b, out);
}